// Round 1
// baseline (278.969 us; speedup 1.0000x reference)
//
#include <hip/hip_runtime.h>

#define BB 8
#define HH 512
#define WW 512
#define K2 9
#define PAD 1
#define HW (HH * WW)

__global__ __launch_bounds__(256) void pp_deconv_kernel(
    const float* __restrict__ depth,   // (B,1,H,W)
    const float* __restrict__ weight,  // (B,K2,H,W)
    const float* __restrict__ offset,  // (B,2*K2,H,W)
    float* __restrict__ out)           // (B,1,H,W)
{
    int idx = blockIdx.x * blockDim.x + threadIdx.x;
    if (idx >= BB * HW) return;

    int b = idx >> 18;          // / HW (262144 = 2^18)
    int p = idx & (HW - 1);
    int y = p >> 9;             // / W (512 = 2^9)
    int x = p & (WW - 1);

    const float* wp   = weight + (size_t)b * K2 * HW + p;
    const float* op   = offset + (size_t)b * 2 * K2 * HW + p;
    const float* dimg = depth  + (size_t)b * HW;

    // ---- weights + mean ----
    float wv[K2];
    float wsum = 0.f;
#pragma unroll
    for (int k = 0; k < K2; ++k) {
        wv[k] = wp[k * HW];
        wsum += wv[k];
    }
    const float wmean = wsum * (1.0f / 9.0f);

    float acc = 0.f;
#pragma unroll
    for (int k = 0; k < K2; ++k) {
        const int ky = k / 3;
        const int kx = k % 3;
        const float dy = op[(2 * k) * HW];
        const float dx = op[(2 * k + 1) * HW];

        const float py = dy + (float)(y - PAD + ky);
        const float px = dx + (float)(x - PAD + kx);

        const float y0f = floorf(py);
        const float x0f = floorf(px);
        const float ty = py - y0f;
        const float tx = px - x0f;
        const int y0 = (int)y0f;
        const int x0 = (int)x0f;
        const int y1 = y0 + 1;
        const int x1 = x0 + 1;

        // clamp indices for the load; zero the contribution if unclipped idx invalid
        const int y0c = min(max(y0, 0), HH - 1);
        const int y1c = min(max(y1, 0), HH - 1);
        const int x0c = min(max(x0, 0), WW - 1);
        const int x1c = min(max(x1, 0), WW - 1);

        const bool vy0 = (y0 >= 0) & (y0 < HH);
        const bool vy1 = (y1 >= 0) & (y1 < HH);
        const bool vx0 = (x0 >= 0) & (x0 < WW);
        const bool vx1 = (x1 >= 0) & (x1 < WW);

        const float v00 = dimg[y0c * WW + x0c];
        const float v01 = dimg[y0c * WW + x1c];
        const float v10 = dimg[y1c * WW + x0c];
        const float v11 = dimg[y1c * WW + x1c];

        const float w00 = (vy0 & vx0) ? (1.f - ty) * (1.f - tx) : 0.f;
        const float w01 = (vy0 & vx1) ? (1.f - ty) * tx         : 0.f;
        const float w10 = (vy1 & vx0) ? ty * (1.f - tx)         : 0.f;
        const float w11 = (vy1 & vx1) ? ty * tx                 : 0.f;

        const float s = v00 * w00 + v01 * w01 + v10 * w10 + v11 * w11;
        acc += s * (wv[k] - wmean);
    }

    out[idx] = acc + dimg[p];
}

extern "C" void kernel_launch(void* const* d_in, const int* in_sizes, int n_in,
                              void* d_out, int out_size, void* d_ws, size_t ws_size,
                              hipStream_t stream) {
    const float* depth  = (const float*)d_in[0];
    const float* weight = (const float*)d_in[1];
    const float* offset = (const float*)d_in[2];
    float* out = (float*)d_out;

    const int total = BB * HW;
    const int block = 256;
    const int grid = (total + block - 1) / block;
    pp_deconv_kernel<<<grid, block, 0, stream>>>(depth, weight, offset, out);
}